// Round 2
// baseline (1035.513 us; speedup 1.0000x reference)
//
#include <hip/hip_runtime.h>
#include <hip/hip_bf16.h>

typedef _Float16 f16;
typedef _Float16 f16x4 __attribute__((ext_vector_type(4)));
typedef _Float16 f16x8 __attribute__((ext_vector_type(8)));
typedef float f32x4 __attribute__((ext_vector_type(4)));

// ---------------------------------------------------------------------------
// BT-GEMM: C[m][n] = sum_k A[m][k] * B[n][k], A,B fp32 row-major (K=1024),
// C written as fp16 with row stride ldc. Used for:
//   q  = X * Wq^T   (A=X [16384x1024], B=Wq [1024x1024], ldc=2048 -> into d_out!)
//   k  = X * Wk^T   (ldc=1024, into ws)
//   vT = Wv * X^T   (A=Wv [1024x1024], B=X, ldc=16384, into ws) -> vT[d][b*4096+n]
// Tile 128x128, BK=64, 4 waves (2x2), 16x16x32 f16 MFMA, fp32->fp16 on stage.
// ---------------------------------------------------------------------------
__global__ __launch_bounds__(256) void proj_gemm(
    const float* __restrict__ A, const float* __restrict__ B,
    f16* __restrict__ C, int ldc)
{
    constexpr int K = 1024, BK = 64;
    __shared__ f16 sA[128 * BK];
    __shared__ f16 sB[128 * BK];
    const int tid = threadIdx.x;
    const int lane = tid & 63, wid = tid >> 6;
    const int wr = wid >> 1, wc = wid & 1;
    const int bm = blockIdx.x * 128, bn = blockIdx.y * 128;

    f32x4 acc[4][4] = {};

    for (int kt = 0; kt < K; kt += BK) {
        __syncthreads();
        {
            const int r0 = tid >> 4;
            const int c4 = (tid & 15) << 2;
#pragma unroll
            for (int p = 0; p < 8; ++p) {
                const int row = (p << 4) + r0;
                const float4 av = *(const float4*)(A + (size_t)(bm + row) * K + kt + c4);
                const float4 bv = *(const float4*)(B + (size_t)(bn + row) * K + kt + c4);
                const int sc = c4 ^ ((row & 7) << 3);
                f16x4 ah = { (f16)av.x, (f16)av.y, (f16)av.z, (f16)av.w };
                f16x4 bh = { (f16)bv.x, (f16)bv.y, (f16)bv.z, (f16)bv.w };
                *(f16x4*)(&sA[(row << 6) + sc]) = ah;
                *(f16x4*)(&sB[(row << 6) + sc]) = bh;
            }
        }
        __syncthreads();
#pragma unroll
        for (int ks = 0; ks < 2; ++ks) {
            const int kk = ks * 32 + (lane >> 4) * 8;
            f16x8 a[4], b[4];
#pragma unroll
            for (int i = 0; i < 4; ++i) {
                const int ra = wr * 64 + i * 16 + (lane & 15);
                a[i] = *(const f16x8*)(&sA[(ra << 6) + (kk ^ ((ra & 7) << 3))]);
                const int rb = wc * 64 + i * 16 + (lane & 15);
                b[i] = *(const f16x8*)(&sB[(rb << 6) + (kk ^ ((rb & 7) << 3))]);
            }
#pragma unroll
            for (int i = 0; i < 4; ++i)
#pragma unroll
                for (int j = 0; j < 4; ++j)
                    acc[i][j] = __builtin_amdgcn_mfma_f32_16x16x32_f16(a[i], b[j], acc[i][j], 0, 0, 0);
        }
    }
#pragma unroll
    for (int i = 0; i < 4; ++i)
#pragma unroll
        for (int j = 0; j < 4; ++j)
#pragma unroll
            for (int r = 0; r < 4; ++r) {
                const int row = bm + wr * 64 + i * 16 + (lane >> 4) * 4 + r;
                const int col = bn + wc * 64 + j * 16 + (lane & 15);
                C[(size_t)row * ldc + col] = (f16)acc[i][j][r];
            }
}

// ---------------------------------------------------------------------------
// Fused flash attention, one head of D=1024.
//   S = Q K^T (no pre-scale!), online softmax, att = (P V) / (l * 32).
// Q lives INTERLEAVED in d_out: q-row at halfs [tok*2048, tok*2048+1024).
// Q rows are block-private; the fp32 epilogue overwrites only this block's
// own (already fully consumed) q rows, so the aliasing is safe.
// NOTE: Q and out alias -> no __restrict__ on them.
// ---------------------------------------------------------------------------
__global__ __launch_bounds__(512) void flash_attn(
    const f16* Q, const f16* __restrict__ Km,
    const f16* __restrict__ VT, float* out)
{
    constexpr int D = 1024, N = 4096, Bq = 64, Bk = 64, DC = 128;
    constexpr int QSTR = 2048;  // q row stride in halfs (interleaved in d_out)
    __shared__ f16 sQ[Bq * DC];
    __shared__ f16 sK[Bk * DC];
    __shared__ float sS[Bq * Bk];
    __shared__ f16 sP[Bq * Bk];
    __shared__ float sm[Bq], sl[Bq], sscale[Bq];

    const int tid = threadIdx.x, lane = tid & 63, wid = tid >> 6;
    const int b = blockIdx.y, qb = blockIdx.x;
    const size_t qbase = ((size_t)b * N + (size_t)qb * Bq) * QSTR;
    const size_t kbase = (size_t)b * N * D;

    if (tid < Bq) { sm[tid] = -1e30f; sl[tid] = 0.0f; }

    f32x4 acc[4][8] = {};
    const int mf = wid & 3, nfq = wid >> 2;

    for (int kt = 0; kt < N / Bk; ++kt) {
        f32x4 accs[2] = {};
        // ---- QK^T over d-chunks ----
        for (int dc = 0; dc < D / DC; ++dc) {
            __syncthreads();
#pragma unroll
            for (int h = 0; h < 2; ++h) {
                const int chunk = tid + h * 512;
                const int row = chunk >> 4;
                const int c8 = (chunk & 15) << 3;
                const int sc = c8 ^ ((row & 7) << 3);
                f16x8 qv = *(const f16x8*)(Q + qbase + (size_t)row * QSTR + dc * DC + c8);
                *(f16x8*)(&sQ[row * DC + sc]) = qv;
                f16x8 kv = *(const f16x8*)(Km + kbase + (size_t)(kt * Bk + row) * D + dc * DC + c8);
                *(f16x8*)(&sK[row * DC + sc]) = kv;
            }
            __syncthreads();
#pragma unroll
            for (int ks = 0; ks < 4; ++ks) {
                const int kk = ks * 32 + (lane >> 4) * 8;
                const int ra = mf * 16 + (lane & 15);
                f16x8 a = *(const f16x8*)(&sQ[ra * DC + (kk ^ ((ra & 7) << 3))]);
#pragma unroll
                for (int f = 0; f < 2; ++f) {
                    const int rb = (nfq + 2 * f) * 16 + (lane & 15);
                    f16x8 bb = *(const f16x8*)(&sK[rb * DC + (kk ^ ((rb & 7) << 3))]);
                    accs[f] = __builtin_amdgcn_mfma_f32_16x16x32_f16(a, bb, accs[f], 0, 0, 0);
                }
            }
        }
        // ---- write S tile ----
#pragma unroll
        for (int f = 0; f < 2; ++f)
#pragma unroll
            for (int r = 0; r < 4; ++r)
                sS[(mf * 16 + (lane >> 4) * 4 + r) * Bk + (nfq + 2 * f) * 16 + (lane & 15)] = accs[f][r];
        __syncthreads();
        // ---- online softmax: wave w owns rows 8w..8w+7, 8 lanes/row ----
        {
            const int row = wid * 8 + (lane >> 3);
            const int c0 = (lane & 7) << 3;
            float v[8];
            float tmax = -1e30f;
#pragma unroll
            for (int j = 0; j < 8; ++j) { v[j] = sS[row * Bk + c0 + j]; tmax = fmaxf(tmax, v[j]); }
#pragma unroll
            for (int msk = 1; msk <= 4; msk <<= 1) tmax = fmaxf(tmax, __shfl_xor(tmax, msk));
            const float mold = sm[row];
            const float mnew = fmaxf(mold, tmax);
            const float scl = __expf(mold - mnew);
            float ps = 0.0f;
#pragma unroll
            for (int j = 0; j < 8; ++j) { v[j] = __expf(v[j] - mnew); ps += v[j]; }
#pragma unroll
            for (int msk = 1; msk <= 4; msk <<= 1) ps += __shfl_xor(ps, msk);
            if ((lane & 7) == 0) {
                sm[row] = mnew;
                sl[row] = sl[row] * scl + ps;
                sscale[row] = scl;
            }
            const int sw = (row & 7) << 3;
#pragma unroll
            for (int j = 0; j < 8; ++j) sP[row * Bk + ((c0 + j) ^ sw)] = (f16)v[j];
        }
        __syncthreads();
        // ---- rescale accumulator + PV ----
        float scl4[4][4];
#pragma unroll
        for (int i = 0; i < 4; ++i)
#pragma unroll
            for (int r = 0; r < 4; ++r)
                scl4[i][r] = sscale[i * 16 + (lane >> 4) * 4 + r];
#pragma unroll
        for (int i = 0; i < 4; ++i)
#pragma unroll
            for (int j = 0; j < 8; ++j)
#pragma unroll
                for (int r = 0; r < 4; ++r) acc[i][j][r] *= scl4[i][r];
#pragma unroll
        for (int ks = 0; ks < 2; ++ks) {
            const int kk = ks * 32 + (lane >> 4) * 8;
            f16x8 a[4];
#pragma unroll
            for (int i = 0; i < 4; ++i) {
                const int ra = i * 16 + (lane & 15);
                a[i] = *(const f16x8*)(&sP[ra * Bk + (kk ^ ((ra & 7) << 3))]);
            }
#pragma unroll
            for (int j = 0; j < 8; ++j) {
                const int dcol = wid * 128 + j * 16 + (lane & 15);
                const f16x8 bb = *(const f16x8*)(VT + (size_t)dcol * 16384 + (size_t)b * N + kt * Bk + kk);
#pragma unroll
                for (int i = 0; i < 4; ++i)
                    acc[i][j] = __builtin_amdgcn_mfma_f32_16x16x32_f16(a[i], bb, acc[i][j], 0, 0, 0);
            }
        }
    }
    __syncthreads();
    // ---- epilogue: att = acc / (32 * l) ----
#pragma unroll
    for (int i = 0; i < 4; ++i) {
        float inv[4];
#pragma unroll
        for (int r = 0; r < 4; ++r) {
            const int row = i * 16 + (lane >> 4) * 4 + r;
            inv[r] = 1.0f / (sl[row] * 32.0f);
        }
#pragma unroll
        for (int j = 0; j < 8; ++j) {
            const int dcol = wid * 128 + j * 16 + (lane & 15);
#pragma unroll
            for (int r = 0; r < 4; ++r) {
                const int row = i * 16 + (lane >> 4) * 4 + r;
                out[((size_t)b * N + (size_t)qb * Bq + row) * D + dcol] = acc[i][j][r] * inv[r];
            }
        }
    }
}

extern "C" void kernel_launch(void* const* d_in, const int* in_sizes, int n_in,
                              void* d_out, int out_size, void* d_ws, size_t ws_size,
                              hipStream_t stream) {
    const float* x  = (const float*)d_in[0];   // [4,4096,1024]
    const float* Wq = (const float*)d_in[1];   // [1024,1024]
    const float* Wk = (const float*)d_in[2];
    const float* Wv = (const float*)d_in[3];
    float* out = (float*)d_out;                // [4,4096,1024] fp32

    const long long NTOK = 16384LL * 1024LL;   // 16.7M elements per tensor
    // ws: 64 MiB total -> k (32 MiB) + vT (32 MiB). q lives interleaved in d_out.
    f16* k  = (f16*)d_ws;
    f16* vT = k + NTOK;
    f16* q  = (f16*)d_out;                     // row stride 2048 halfs (4 KB)

    // q = X Wq^T  (into d_out, interleaved, ldc=2048)
    proj_gemm<<<dim3(128, 8), 256, 0, stream>>>(x, Wq, q, 2048);
    // k = X Wk^T  (ws, ldc=1024)
    proj_gemm<<<dim3(128, 8), 256, 0, stream>>>(x, Wk, k, 1024);
    // vT = Wv X^T (ws, ldc=16384)
    proj_gemm<<<dim3(8, 128), 256, 0, stream>>>(Wv, x, vT, 16384);

    // fused attention: grid (4096/64 q-blocks, 4 batches)
    flash_attn<<<dim3(64, 4), 512, 0, stream>>>(q, k, vT, out);
}